// Round 1
// baseline (433.311 us; speedup 1.0000x reference)
//
#include <hip/hip_runtime.h>
#include <math.h>

#define N_B   16
#define C_IN  256
#define MIP   64
#define HW    96
#define PTOT  192   // 2*HW
#define KK    7

// ---------------------------------------------------------------------------
// Kernel A: per-(n,c) plane -> row means (x_h) and col means (x_w)
// pooled layout: pooled[(n*C_IN + c)*192 + p], p<96: row-mean[i], p>=96: col-mean[j]
// ---------------------------------------------------------------------------
__global__ void pool_kernel(const float* __restrict__ x, float* __restrict__ pooled) {
    int plane = blockIdx.x;                       // n*256 + c
    const float* xp = x + (size_t)plane * (HW * HW);
    __shared__ float sm[HW * 97];                 // padded stride 97
    int t = threadIdx.x;
    // stage plane: 2304 float4, 256 threads x 9
    #pragma unroll
    for (int k = 0; k < 9; ++k) {
        int idx = t + k * 256;                    // float4 index
        float4 v = ((const float4*)xp)[idx];
        int flat = idx * 4;
        int row = flat / HW;                      // 96 % 4 == 0: float4 never crosses rows
        int col = flat - row * HW;
        float* d = &sm[row * 97 + col];
        d[0] = v.x; d[1] = v.y; d[2] = v.z; d[3] = v.w;
    }
    __syncthreads();
    if (t < HW) {
        float rs = 0.f, cs = 0.f;
        #pragma unroll 4
        for (int j = 0; j < HW; ++j) rs += sm[t * 97 + j];
        #pragma unroll 4
        for (int i = 0; i < HW; ++i) cs += sm[i * 97 + t];
        float* pp = pooled + (size_t)plane * PTOT;
        pp[t]      = rs * (1.f / 96.f);
        pp[HW + t] = cs * (1.f / 96.f);
    }
}

// ---------------------------------------------------------------------------
// Kernel B: y[n][ch][p] = hswish(BN(involution1(conv1x1(pooled))))
// one block per (p, n); recomputes conv at the 7-neighborhood
// ---------------------------------------------------------------------------
__global__ void mid1_kernel(const float* __restrict__ pooled,
                            const float* __restrict__ w_c1, const float* __restrict__ b_c1,
                            const float* __restrict__ w1,   const float* __restrict__ b1,
                            const float* __restrict__ w2,   const float* __restrict__ b2,
                            const float* __restrict__ bn_g, const float* __restrict__ bn_b,
                            const float* __restrict__ bn_m, const float* __restrict__ bn_v,
                            float* __restrict__ y) {
    int p = blockIdx.x;     // 0..191
    int n = blockIdx.y;     // 0..15
    __shared__ float lpool[C_IN * KK];   // [c][k]
    __shared__ float ly0[KK][MIP];       // conv output at 7 positions
    __shared__ float lt[16];
    __shared__ float lwgt[28];           // [g][ky]
    int t = threadIdx.x;
    const float* pn = pooled + (size_t)n * C_IN * PTOT;

    // stage pooled neighborhood (zero-pad handled later via ly0 guard; here just clamp-read)
    #pragma unroll
    for (int it = 0; it < 7; ++it) {
        int flat = t + it * 256;                 // 1792 = 256*7
        int c = flat / KK, k = flat - (flat / KK) * KK;
        int pp = p + k - 3;
        lpool[flat] = (pp >= 0 && pp < PTOT) ? pn[c * PTOT + pp] : 0.f;
    }
    __syncthreads();

    // conv1x1 256->64 at 7 positions: 448 outputs
    for (int rep = 0; rep < 2; ++rep) {
        int idx = t + rep * 256;
        if (idx < MIP * KK) {
            int o = idx / KK, k = idx - o * KK;
            int pp = p + k - 3;
            float acc = 0.f;
            if (pp >= 0 && pp < PTOT) {          // involution zero-pads its input
                const float* wrow = w_c1 + o * C_IN;
                #pragma unroll 8
                for (int c = 0; c < C_IN; ++c) acc += wrow[c] * lpool[c * KK + k];
                acc += b_c1[o];
            }
            ly0[k][o] = acc;
        }
    }
    __syncthreads();

    // wgt conv stage 1: 64 -> 16 at center position
    if (t < 16) {
        float acc = b1[t];
        const float* wr = w1 + t * MIP;
        #pragma unroll 8
        for (int o = 0; o < MIP; ++o) acc += wr[o] * ly0[3][o];
        lt[t] = acc;
    }
    __syncthreads();

    // wgt conv stage 2: only taps k = ky*7+3 matter (width-1 spatial)
    if (t < 28) {
        int g = t / KK, ky = t - g * KK;
        int q = g * 49 + ky * KK + 3;
        float acc = b2[q];
        const float* wr = w2 + q * 16;
        #pragma unroll
        for (int r = 0; r < 16; ++r) acc += wr[r] * lt[r];
        lwgt[t] = acc;
    }
    __syncthreads();

    // apply involution + BN + hswish
    if (t < MIP) {
        int g = t >> 4;
        float acc = 0.f;
        #pragma unroll
        for (int ky = 0; ky < KK; ++ky) acc += lwgt[g * KK + ky] * ly0[ky][t];
        float inv_std = rsqrtf(bn_v[t] + 1e-5f);
        float v = (acc - bn_m[t]) * (bn_g[t] * inv_std) + bn_b[t];
        float hs = v * fminf(fmaxf(v + 3.f, 0.f), 6.f) * (1.f / 6.f);
        y[((size_t)n * MIP + t) * PTOT + p] = hs;
    }
}

// ---------------------------------------------------------------------------
// Kernel C: a_h / a_w = sigmoid(conv1x1(involution(y_half)))
// block (p,n); p<96 -> H side (taps ky*7+3), p>=96 -> W side (taps 21+kx)
// ---------------------------------------------------------------------------
__global__ void mid2_kernel(const float* __restrict__ y,
                            const float* __restrict__ h_w1, const float* __restrict__ h_b1,
                            const float* __restrict__ h_w2, const float* __restrict__ h_b2,
                            const float* __restrict__ w_h,  const float* __restrict__ b_h,
                            const float* __restrict__ v_w1, const float* __restrict__ v_b1,
                            const float* __restrict__ v_w2, const float* __restrict__ v_b2,
                            const float* __restrict__ w_w,  const float* __restrict__ b_w,
                            float* __restrict__ a_h, float* __restrict__ a_w) {
    int p = blockIdx.x;     // 0..191
    int n = blockIdx.y;
    int side = (p >= HW) ? 1 : 0;
    int pos = side ? (p - HW) : p;
    const float* w1 = side ? v_w1 : h_w1;
    const float* b1 = side ? v_b1 : h_b1;
    const float* w2 = side ? v_w2 : h_w2;
    const float* b2 = side ? v_b2 : h_b2;
    const float* wf = side ? w_w : w_h;
    const float* bf = side ? b_w : b_h;

    __shared__ float ly[KK][MIP];
    __shared__ float lt[16];
    __shared__ float lwgt[28];
    __shared__ float lz[MIP];
    int t = threadIdx.x;
    const float* yn = y + (size_t)n * MIP * PTOT;

    // stage 7-neighborhood of this half (zero pad outside [0,96))
    for (int rep = 0; rep < 2; ++rep) {
        int idx = t + rep * 256;
        if (idx < MIP * KK) {
            int ch = idx / KK, k = idx - (idx / KK) * KK;
            int q = pos + k - 3;
            float v = 0.f;
            if (q >= 0 && q < HW) v = yn[ch * PTOT + (side ? (HW + q) : q)];
            ly[k][ch] = v;
        }
    }
    __syncthreads();

    if (t < 16) {
        float acc = b1[t];
        const float* wr = w1 + t * MIP;
        #pragma unroll 8
        for (int o = 0; o < MIP; ++o) acc += wr[o] * ly[3][o];
        lt[t] = acc;
    }
    __syncthreads();

    if (t < 28) {
        int g = t / KK, kk = t - (t / KK) * KK;
        int q = side ? (g * 49 + 21 + kk) : (g * 49 + kk * KK + 3);
        float acc = b2[q];
        const float* wr = w2 + q * 16;
        #pragma unroll
        for (int r = 0; r < 16; ++r) acc += wr[r] * lt[r];
        lwgt[t] = acc;
    }
    __syncthreads();

    if (t < MIP) {
        int g = t >> 4;
        float acc = 0.f;
        #pragma unroll
        for (int k = 0; k < KK; ++k) acc += lwgt[g * KK + k] * ly[k][t];
        lz[t] = acc;
    }
    __syncthreads();

    // final conv 64->256 + sigmoid, one output per thread
    {
        int co = t;
        const float* wr = wf + co * MIP;
        float acc = bf[co];
        #pragma unroll 8
        for (int ch = 0; ch < MIP; ++ch) acc += wr[ch] * lz[ch];
        float a = 1.f / (1.f + __expf(-acc));
        float* dst = side ? a_w : a_h;
        dst[((size_t)n * C_IN + co) * HW + pos] = a;
    }
}

// ---------------------------------------------------------------------------
// Kernel D: out = x * a_w[j] * a_h[i], per-plane, float4
// ---------------------------------------------------------------------------
__global__ void apply_kernel(const float* __restrict__ x,
                             const float* __restrict__ a_h, const float* __restrict__ a_w,
                             float* __restrict__ out) {
    int plane = blockIdx.x;   // n*256 + c
    const float4* xp = (const float4*)(x + (size_t)plane * (HW * HW));
    float4* op = (float4*)(out + (size_t)plane * (HW * HW));
    __shared__ float sah[HW];
    __shared__ float saw[HW];
    int t = threadIdx.x;
    if (t < HW) {
        sah[t] = a_h[(size_t)plane * HW + t];
        saw[t] = a_w[(size_t)plane * HW + t];
    }
    __syncthreads();
    #pragma unroll
    for (int k = 0; k < 9; ++k) {
        int idx = t + k * 256;          // float4 index, 2304 per plane
        float4 v = xp[idx];
        int row = idx / 24;             // 24 float4 per row
        int c4 = (idx - row * 24) * 4;
        float ah = sah[row];
        v.x *= ah * saw[c4 + 0];
        v.y *= ah * saw[c4 + 1];
        v.z *= ah * saw[c4 + 2];
        v.w *= ah * saw[c4 + 3];
        op[idx] = v;
    }
}

extern "C" void kernel_launch(void* const* d_in, const int* in_sizes, int n_in,
                              void* d_out, int out_size, void* d_ws, size_t ws_size,
                              hipStream_t stream) {
    const float* x      = (const float*)d_in[0];
    const float* w_c1   = (const float*)d_in[1];
    const float* b_c1   = (const float*)d_in[2];
    const float* i1_w1  = (const float*)d_in[3];
    const float* i1_b1  = (const float*)d_in[4];
    const float* i1_w2  = (const float*)d_in[5];
    const float* i1_b2  = (const float*)d_in[6];
    const float* bn_g   = (const float*)d_in[7];
    const float* bn_b   = (const float*)d_in[8];
    const float* bn_m   = (const float*)d_in[9];
    const float* bn_v   = (const float*)d_in[10];
    const float* ih_w1  = (const float*)d_in[11];
    const float* ih_b1  = (const float*)d_in[12];
    const float* ih_w2  = (const float*)d_in[13];
    const float* ih_b2  = (const float*)d_in[14];
    const float* w_h    = (const float*)d_in[15];
    const float* b_h    = (const float*)d_in[16];
    const float* iw_w1  = (const float*)d_in[17];
    const float* iw_b1  = (const float*)d_in[18];
    const float* iw_w2  = (const float*)d_in[19];
    const float* iw_b2  = (const float*)d_in[20];
    const float* w_w    = (const float*)d_in[21];
    const float* b_w    = (const float*)d_in[22];
    float* out = (float*)d_out;

    float* ws = (float*)d_ws;
    float* pooled = ws;                                   // 16*256*192 = 786432
    float* y      = ws + 786432;                          // 16*64*192  = 196608
    float* a_h    = ws + 786432 + 196608;                 // 16*256*96  = 393216
    float* a_w    = ws + 786432 + 196608 + 393216;        // 16*256*96  = 393216

    pool_kernel<<<dim3(N_B * C_IN), dim3(256), 0, stream>>>(x, pooled);
    mid1_kernel<<<dim3(PTOT, N_B), dim3(256), 0, stream>>>(
        pooled, w_c1, b_c1, i1_w1, i1_b1, i1_w2, i1_b2,
        bn_g, bn_b, bn_m, bn_v, y);
    mid2_kernel<<<dim3(PTOT, N_B), dim3(256), 0, stream>>>(
        y, ih_w1, ih_b1, ih_w2, ih_b2, w_h, b_h,
        iw_w1, iw_b1, iw_w2, iw_b2, w_w, b_w, a_h, a_w);
    apply_kernel<<<dim3(N_B * C_IN), dim3(256), 0, stream>>>(x, a_h, a_w, out);
}

// Round 2
// 359.901 us; speedup vs baseline: 1.2040x; 1.2040x over previous
//
#include <hip/hip_runtime.h>
#include <math.h>

#define N_B   16
#define C_IN  256
#define MIP   64
#define HW    96
#define PTOT  192   // 2*HW
#define KK    7

// ---------------------------------------------------------------------------
// Kernel P: transpose final conv weights (256x64 -> 64x256), both branches
// ---------------------------------------------------------------------------
__global__ void prep_kernel(const float* __restrict__ w_h, const float* __restrict__ w_w,
                            float* __restrict__ wfT_h, float* __restrict__ wfT_w) {
    int idx = blockIdx.x * 256 + threadIdx.x;     // 0..32767
    int sel = idx >> 14;                          // 0: h, 1: w
    int rem = idx & 16383;
    int co = rem >> 6;                            // 0..255
    int ch = rem & 63;                            // 0..63
    const float* src = sel ? w_w : w_h;
    float* dst = sel ? wfT_w : wfT_h;
    dst[ch * C_IN + co] = src[co * MIP + ch];
}

// ---------------------------------------------------------------------------
// Kernel A: per-(n,c) plane -> row means and col means
// pooled[(n*256 + c)*192 + p]; p<96: row-mean[p], p>=96: col-mean[p-96]
// ---------------------------------------------------------------------------
__global__ void pool_kernel(const float* __restrict__ x, float* __restrict__ pooled) {
    int plane = blockIdx.x;                       // n*256 + c
    const float* xp = x + (size_t)plane * (HW * HW);
    __shared__ float sm[HW * 97];                 // padded stride 97
    int t = threadIdx.x;
    #pragma unroll
    for (int k = 0; k < 9; ++k) {
        int idx = t + k * 256;                    // float4 index
        float4 v = ((const float4*)xp)[idx];
        int flat = idx * 4;
        int row = flat / HW;
        int col = flat - row * HW;
        float* d = &sm[row * 97 + col];
        d[0] = v.x; d[1] = v.y; d[2] = v.z; d[3] = v.w;
    }
    __syncthreads();
    float* pp = pooled + (size_t)plane * PTOT;
    if (t < HW) {
        float rs = 0.f;
        #pragma unroll 4
        for (int j = 0; j < HW; ++j) rs += sm[t * 97 + j];
        pp[t] = rs * (1.f / 96.f);
    } else if (t < 2 * HW) {
        int c = t - HW;
        float cs = 0.f;
        #pragma unroll 4
        for (int i = 0; i < HW; ++i) cs += sm[i * 97 + c];
        pp[HW + c] = cs * (1.f / 96.f);
    }
}

// ---------------------------------------------------------------------------
// Kernel B0: conv1x1 256->64 over all 192 positions (once, no redundancy)
// y0 layout: y0[((n*192)+p)*64 + o]
// ---------------------------------------------------------------------------
__global__ void conv0_kernel(const float* __restrict__ pooled,
                             const float* __restrict__ w_c1, const float* __restrict__ b_c1,
                             float* __restrict__ y0) {
    int p0 = blockIdx.x * 16;   // 12 tiles
    int n  = blockIdx.y;
    int t  = threadIdx.x;
    __shared__ float pt[C_IN * 16];     // [c][pl]  16 KB
    __shared__ float sw[64 * 65];       // [o][cc]  padded
    const float* pn = pooled + (size_t)n * C_IN * PTOT;

    #pragma unroll
    for (int i = 0; i < 16; ++i) {
        int flat = t + 256 * i;
        int c = flat >> 4, pl = flat & 15;
        pt[flat] = pn[c * PTOT + p0 + pl];
    }

    int o = t & 63;
    int pl0 = (t >> 6) * 4;
    float acc0 = 0.f, acc1 = 0.f, acc2 = 0.f, acc3 = 0.f;

    for (int c0 = 0; c0 < C_IN; c0 += 64) {
        __syncthreads();
        #pragma unroll
        for (int i = 0; i < 16; ++i) {
            int flat = t + 256 * i;
            int oo = flat >> 6, cc = flat & 63;
            sw[oo * 65 + cc] = w_c1[oo * C_IN + c0 + cc];
        }
        __syncthreads();
        #pragma unroll 8
        for (int cc = 0; cc < 64; ++cc) {
            float wv = sw[o * 65 + cc];
            const float4 pv = *(const float4*)&pt[(c0 + cc) * 16 + pl0];
            acc0 += wv * pv.x;
            acc1 += wv * pv.y;
            acc2 += wv * pv.z;
            acc3 += wv * pv.w;
        }
    }
    float b = b_c1[o];
    size_t base = ((size_t)n * PTOT + p0 + pl0) * MIP + o;
    y0[base]            = acc0 + b;
    y0[base + MIP]      = acc1 + b;
    y0[base + 2 * MIP]  = acc2 + b;
    y0[base + 3 * MIP]  = acc3 + b;
}

// ---------------------------------------------------------------------------
// Kernel B1: y = hswish(BN(involution1(y0)))  -- 64 threads per (p,n)
// y layout: y[((n*192)+p)*64 + ch]
// ---------------------------------------------------------------------------
__global__ void mid1_kernel(const float* __restrict__ y0,
                            const float* __restrict__ w1,   const float* __restrict__ b1,
                            const float* __restrict__ w2,   const float* __restrict__ b2,
                            const float* __restrict__ bn_g, const float* __restrict__ bn_b,
                            const float* __restrict__ bn_m, const float* __restrict__ bn_v,
                            float* __restrict__ y) {
    int p = blockIdx.x;     // 0..191
    int n = blockIdx.y;
    int t = threadIdx.x;    // 0..63
    __shared__ float ly0[KK][MIP];
    __shared__ float lt[16];
    __shared__ float lwgt[28];
    const float* yn = y0 + (size_t)n * PTOT * MIP;

    #pragma unroll
    for (int k = 0; k < KK; ++k) {
        int pp = p + k - 3;
        ly0[k][t] = (pp >= 0 && pp < PTOT) ? yn[pp * MIP + t] : 0.f;
    }
    __syncthreads();

    if (t < 16) {
        float acc = b1[t];
        const float* wr = w1 + t * MIP;
        #pragma unroll 8
        for (int o = 0; o < MIP; ++o) acc += wr[o] * ly0[3][o];
        lt[t] = acc;
    }
    __syncthreads();

    if (t < 28) {
        int g = t / KK, ky = t - g * KK;
        int q = g * 49 + ky * KK + 3;
        float acc = b2[q];
        const float* wr = w2 + q * 16;
        #pragma unroll
        for (int r = 0; r < 16; ++r) acc += wr[r] * lt[r];
        lwgt[t] = acc;
    }
    __syncthreads();

    {
        int g = t >> 4;
        float acc = 0.f;
        #pragma unroll
        for (int ky = 0; ky < KK; ++ky) acc += lwgt[g * KK + ky] * ly0[ky][t];
        float inv_std = rsqrtf(bn_v[t] + 1e-5f);
        float v = (acc - bn_m[t]) * (bn_g[t] * inv_std) + bn_b[t];
        float hs = v * fminf(fmaxf(v + 3.f, 0.f), 6.f) * (1.f / 6.f);
        y[((size_t)n * PTOT + p) * MIP + t] = hs;
    }
}

// ---------------------------------------------------------------------------
// Kernel C: a_h / a_w = sigmoid(conv1x1(involution(y_half))) -- 64 threads
// ---------------------------------------------------------------------------
__global__ void mid2_kernel(const float* __restrict__ y,
                            const float* __restrict__ h_w1, const float* __restrict__ h_b1,
                            const float* __restrict__ h_w2, const float* __restrict__ h_b2,
                            const float* __restrict__ wfT_h, const float* __restrict__ b_h,
                            const float* __restrict__ v_w1, const float* __restrict__ v_b1,
                            const float* __restrict__ v_w2, const float* __restrict__ v_b2,
                            const float* __restrict__ wfT_w, const float* __restrict__ b_w,
                            float* __restrict__ a_h, float* __restrict__ a_w) {
    int p = blockIdx.x;     // 0..191
    int n = blockIdx.y;
    int t = threadIdx.x;    // 0..63
    int side = (p >= HW) ? 1 : 0;
    int pos = side ? (p - HW) : p;
    const float* w1 = side ? v_w1 : h_w1;
    const float* b1 = side ? v_b1 : h_b1;
    const float* w2 = side ? v_w2 : h_w2;
    const float* b2 = side ? v_b2 : h_b2;
    const float* wf = side ? wfT_w : wfT_h;
    const float* bf = side ? b_w : b_h;

    __shared__ float ly[KK][MIP];
    __shared__ float lt[16];
    __shared__ float lwgt[28];
    __shared__ float lz[MIP];
    const float* yn = y + (size_t)n * PTOT * MIP;

    #pragma unroll
    for (int k = 0; k < KK; ++k) {
        int q = pos + k - 3;
        float v = 0.f;
        if (q >= 0 && q < HW) v = yn[(side ? (HW + q) : q) * MIP + t];
        ly[k][t] = v;
    }
    __syncthreads();

    if (t < 16) {
        float acc = b1[t];
        const float* wr = w1 + t * MIP;
        #pragma unroll 8
        for (int o = 0; o < MIP; ++o) acc += wr[o] * ly[3][o];
        lt[t] = acc;
    }
    __syncthreads();

    if (t < 28) {
        int g = t / KK, kk = t - (t / KK) * KK;
        int q = side ? (g * 49 + 21 + kk) : (g * 49 + kk * KK + 3);
        float acc = b2[q];
        const float* wr = w2 + q * 16;
        #pragma unroll
        for (int r = 0; r < 16; ++r) acc += wr[r] * lt[r];
        lwgt[t] = acc;
    }
    __syncthreads();

    {
        int g = t >> 4;
        float acc = 0.f;
        #pragma unroll
        for (int k = 0; k < KK; ++k) acc += lwgt[g * KK + k] * ly[k][t];
        lz[t] = acc;
    }
    __syncthreads();

    float* dst = side ? a_w : a_h;
    #pragma unroll
    for (int q = 0; q < 4; ++q) {
        int co = q * 64 + t;
        float acc = bf[co];
        #pragma unroll 8
        for (int ch = 0; ch < MIP; ++ch) acc += wf[ch * C_IN + co] * lz[ch];
        float a = 1.f / (1.f + __expf(-acc));
        dst[((size_t)n * C_IN + co) * HW + pos] = a;
    }
}

// ---------------------------------------------------------------------------
// Kernel D: out = x * a_w[j] * a_h[i], per-plane, float4
// ---------------------------------------------------------------------------
__global__ void apply_kernel(const float* __restrict__ x,
                             const float* __restrict__ a_h, const float* __restrict__ a_w,
                             float* __restrict__ out) {
    int plane = blockIdx.x;   // n*256 + c
    const float4* xp = (const float4*)(x + (size_t)plane * (HW * HW));
    float4* op = (float4*)(out + (size_t)plane * (HW * HW));
    __shared__ float sah[HW];
    __shared__ float saw[HW];
    int t = threadIdx.x;
    if (t < HW) {
        sah[t] = a_h[(size_t)plane * HW + t];
        saw[t] = a_w[(size_t)plane * HW + t];
    }
    __syncthreads();
    #pragma unroll
    for (int k = 0; k < 9; ++k) {
        int idx = t + k * 256;          // float4 index, 2304 per plane
        float4 v = xp[idx];
        int row = idx / 24;
        int c4 = (idx - row * 24) * 4;
        float ah = sah[row];
        v.x *= ah * saw[c4 + 0];
        v.y *= ah * saw[c4 + 1];
        v.z *= ah * saw[c4 + 2];
        v.w *= ah * saw[c4 + 3];
        op[idx] = v;
    }
}

extern "C" void kernel_launch(void* const* d_in, const int* in_sizes, int n_in,
                              void* d_out, int out_size, void* d_ws, size_t ws_size,
                              hipStream_t stream) {
    const float* x      = (const float*)d_in[0];
    const float* w_c1   = (const float*)d_in[1];
    const float* b_c1   = (const float*)d_in[2];
    const float* i1_w1  = (const float*)d_in[3];
    const float* i1_b1  = (const float*)d_in[4];
    const float* i1_w2  = (const float*)d_in[5];
    const float* i1_b2  = (const float*)d_in[6];
    const float* bn_g   = (const float*)d_in[7];
    const float* bn_b   = (const float*)d_in[8];
    const float* bn_m   = (const float*)d_in[9];
    const float* bn_v   = (const float*)d_in[10];
    const float* ih_w1  = (const float*)d_in[11];
    const float* ih_b1  = (const float*)d_in[12];
    const float* ih_w2  = (const float*)d_in[13];
    const float* ih_b2  = (const float*)d_in[14];
    const float* w_h    = (const float*)d_in[15];
    const float* b_h    = (const float*)d_in[16];
    const float* iw_w1  = (const float*)d_in[17];
    const float* iw_b1  = (const float*)d_in[18];
    const float* iw_w2  = (const float*)d_in[19];
    const float* iw_b2  = (const float*)d_in[20];
    const float* w_w    = (const float*)d_in[21];
    const float* b_w    = (const float*)d_in[22];
    float* out = (float*)d_out;

    float* ws = (float*)d_ws;
    float* pooled = ws;                       // 786432
    float* y0     = pooled + 786432;          // 196608
    float* y      = y0 + 196608;              // 196608
    float* a_h    = y + 196608;               // 393216
    float* a_w    = a_h + 393216;             // 393216
    float* wfT_h  = a_w + 393216;             // 16384
    float* wfT_w  = wfT_h + 16384;            // 16384

    prep_kernel<<<dim3(128), dim3(256), 0, stream>>>(w_h, w_w, wfT_h, wfT_w);
    pool_kernel<<<dim3(N_B * C_IN), dim3(256), 0, stream>>>(x, pooled);
    conv0_kernel<<<dim3(12, N_B), dim3(256), 0, stream>>>(pooled, w_c1, b_c1, y0);
    mid1_kernel<<<dim3(PTOT, N_B), dim3(64), 0, stream>>>(
        y0, i1_w1, i1_b1, i1_w2, i1_b2, bn_g, bn_b, bn_m, bn_v, y);
    mid2_kernel<<<dim3(PTOT, N_B), dim3(64), 0, stream>>>(
        y, ih_w1, ih_b1, ih_w2, ih_b2, wfT_h, b_h,
        iw_w1, iw_b1, iw_w2, iw_b2, wfT_w, b_w, a_h, a_w);
    apply_kernel<<<dim3(N_B * C_IN), dim3(256), 0, stream>>>(x, a_h, a_w, out);
}

// Round 4
// 350.489 us; speedup vs baseline: 1.2363x; 1.0269x over previous
//
#include <hip/hip_runtime.h>
#include <math.h>

#define N_B   16
#define C_IN  256
#define MIP   64
#define HW    96
#define PTOT  192   // 2*HW
#define KK    7

typedef float floatx4 __attribute__((ext_vector_type(4)));

// ---------------------------------------------------------------------------
// Kernel A: per-(n,c) plane -> row means and col means
// pooled[(n*256 + c)*192 + p]; p<96: row-mean[p], p>=96: col-mean[p-96]
// ---------------------------------------------------------------------------
__global__ void pool_kernel(const float* __restrict__ x, float* __restrict__ pooled) {
    int plane = blockIdx.x;                       // n*256 + c
    const float* xp = x + (size_t)plane * (HW * HW);
    __shared__ float sm[HW * 97];                 // padded stride 97
    int t = threadIdx.x;
    #pragma unroll
    for (int k = 0; k < 9; ++k) {
        int idx = t + k * 256;                    // float4 index
        floatx4 v = ((const floatx4*)xp)[idx];
        int flat = idx * 4;
        int row = flat / HW;
        int col = flat - row * HW;
        float* d = &sm[row * 97 + col];
        d[0] = v.x; d[1] = v.y; d[2] = v.z; d[3] = v.w;
    }
    __syncthreads();
    float* pp = pooled + (size_t)plane * PTOT;
    if (t < HW) {
        float rs = 0.f;
        #pragma unroll 4
        for (int j = 0; j < HW; ++j) rs += sm[t * 97 + j];
        pp[t] = rs * (1.f / 96.f);
    } else if (t < 2 * HW) {
        int c = t - HW;
        float cs = 0.f;
        #pragma unroll 4
        for (int i = 0; i < HW; ++i) cs += sm[i * 97 + c];
        pp[HW + c] = cs * (1.f / 96.f);
    }
}

// ---------------------------------------------------------------------------
// Kernel B: the ENTIRE mid pipeline in one kernel.
// Block = 16 final positions (tile) x batch n. 12x16 = 192 blocks, 256 thr.
// Chain of halos: final tile [p0,p0+16) needs y at [p0-3,p0+18] (22 pos),
// which needs y0 = conv0 at [p0-6,p0+21] (28 pos). conv recompute = 1.75x
// of a ~100 MFLOP conv -> negligible. Tiles never straddle the 96 boundary
// (96 = 6*16), so the h/w branch is block-uniform.
// ---------------------------------------------------------------------------
__global__ __launch_bounds__(256) void megamid_kernel(
    const float* __restrict__ pooled,
    const float* __restrict__ w_c1, const float* __restrict__ b_c1,
    const float* __restrict__ i1_w1, const float* __restrict__ i1_b1,
    const float* __restrict__ i1_w2, const float* __restrict__ i1_b2,
    const float* __restrict__ bn_g, const float* __restrict__ bn_b,
    const float* __restrict__ bn_m, const float* __restrict__ bn_v,
    const float* __restrict__ h_w1, const float* __restrict__ h_b1,
    const float* __restrict__ h_w2, const float* __restrict__ h_b2,
    const float* __restrict__ w_h,  const float* __restrict__ b_h,
    const float* __restrict__ v_w1, const float* __restrict__ v_b1,
    const float* __restrict__ v_w2, const float* __restrict__ v_b2,
    const float* __restrict__ w_w,  const float* __restrict__ b_w,
    float* __restrict__ a_h, float* __restrict__ a_w)
{
    int p0 = blockIdx.x * 16;      // tile start, 0..176
    int n  = blockIdx.y;
    int t  = threadIdx.x;
    int side = (p0 >= HW) ? 1 : 0; // uniform per block
    int lo = side * HW;

    // 15552 floats = 60.75 KB, with region reuse (pt is dead after conv)
    __shared__ float smem[15552];
    float* pt   = smem;            // [c*32 + j], j = r-(p0-6), 28 used, 8192
    float* sw   = smem + 8192;     // [o*65 + cc], 4160
    float* y0t  = smem + 12352;    // [j*64 + o], j in [0,28), 1792
    float* yt   = smem + 14144;    // [q*64 + ch], q in [0,22), 1408
    // region reuse of pt after conv:
    float* lt    = smem;           // 22*16 = 352
    float* lwgt  = smem + 352;     // 22*28 = 616
    float* lt2   = smem + 968;     // 16*16 = 256
    float* lwgt2 = smem + 1224;    // 16*28 = 448
    float* lz    = smem + 1672;    // 16*64 = 1024

    const float* pn = pooled + (size_t)n * C_IN * PTOT;

    // ---- stage pooled neighborhood (zero outside [0,192)) ----
    #pragma unroll
    for (int i = 0; i < 32; ++i) {
        int flat = t + 256 * i;
        int c = flat >> 5, j = flat & 31;
        int r = p0 - 6 + j;
        pt[flat] = (j < 28 && r >= 0 && r < PTOT) ? pn[c * PTOT + r] : 0.f;
    }

    // ---- conv1x1 256->64 at 28 (padded 32) positions ----
    int o = t & 63;
    int j0 = (t >> 6) * 8;         // 8 consecutive positions per thread
    float acc[8];
    #pragma unroll
    for (int e = 0; e < 8; ++e) acc[e] = 0.f;

    for (int c0 = 0; c0 < C_IN; c0 += 64) {
        __syncthreads();
        #pragma unroll
        for (int i = 0; i < 16; ++i) {
            int flat = t + 256 * i;
            int oo = flat >> 6, cc = flat & 63;
            sw[oo * 65 + cc] = w_c1[oo * C_IN + c0 + cc];
        }
        __syncthreads();
        #pragma unroll 4
        for (int cc = 0; cc < 64; ++cc) {
            float wv = sw[o * 65 + cc];
            const floatx4 pa = *(const floatx4*)&pt[(c0 + cc) * 32 + j0];
            const floatx4 pb = *(const floatx4*)&pt[(c0 + cc) * 32 + j0 + 4];
            acc[0] += wv * pa.x; acc[1] += wv * pa.y;
            acc[2] += wv * pa.z; acc[3] += wv * pa.w;
            acc[4] += wv * pb.x; acc[5] += wv * pb.y;
            acc[6] += wv * pb.z; acc[7] += wv * pb.w;
        }
    }
    // involution1 zero-pads its INPUT (conv output incl bias) outside [0,192)
    {
        float bo = b_c1[o];
        #pragma unroll
        for (int e = 0; e < 8; ++e) {
            int j = j0 + e;
            if (j < 28) {
                int r = p0 - 6 + j;
                y0t[j * 64 + o] = (r >= 0 && r < PTOT) ? (acc[e] + bo) : 0.f;
            }
        }
    }
    __syncthreads();   // y0t visible; all pt reads done -> region1 reusable

    // ---- mid1: lt = w1 . y0(center), 22 pos x 16 ----
    for (int idx = t; idx < 352; idx += 256) {
        int q = idx >> 4, i = idx & 15;
        float a = i1_b1[i];
        const float* wr = i1_w1 + i * MIP;
        #pragma unroll 8
        for (int oo = 0; oo < MIP; ++oo) a += wr[oo] * y0t[(q + 3) * 64 + oo];
        lt[idx] = a;
    }
    __syncthreads();
    // ---- mid1: lwgt (only taps ky*7+3 survive on the (192,1) map) ----
    for (int idx = t; idx < 616; idx += 256) {
        int q = idx / 28, m = idx - q * 28;
        int g = m / 7, ky = m - g * 7;
        int wq = g * 49 + ky * 7 + 3;
        float a = i1_b2[wq];
        const float* wr = i1_w2 + wq * 16;
        #pragma unroll
        for (int r = 0; r < 16; ++r) a += wr[r] * lt[q * 16 + r];
        lwgt[idx] = a;
    }
    __syncthreads();
    // ---- mid1: involution + BN + hswish -> yt, 22 pos x 64 ch ----
    for (int idx = t; idx < 1408; idx += 256) {
        int q = idx >> 6, ch = idx & 63;
        int g = ch >> 4;
        float a = 0.f;
        #pragma unroll
        for (int ky = 0; ky < KK; ++ky)
            a += lwgt[q * 28 + g * 7 + ky] * y0t[(q + ky) * 64 + ch];
        float inv_std = rsqrtf(bn_v[ch] + 1e-5f);
        float v = (a - bn_m[ch]) * (bn_g[ch] * inv_std) + bn_b[ch];
        yt[idx] = v * fminf(fmaxf(v + 3.f, 0.f), 6.f) * (1.f / 6.f);
    }
    __syncthreads();

    // ---- mid2 (branch weights uniform per block) ----
    const float* ww1 = side ? v_w1 : h_w1;
    const float* bb1 = side ? v_b1 : h_b1;
    const float* ww2 = side ? v_w2 : h_w2;
    const float* bb2 = side ? v_b2 : h_b2;
    const float* wf  = side ? w_w  : w_h;
    const float* bf  = side ? b_w  : b_h;

    // lt2: 16 pos x 16 (center p0+pp is always inside the half)
    {
        int pp = t >> 4, i = t & 15;
        float a = bb1[i];
        const float* wr = ww1 + i * MIP;
        #pragma unroll 8
        for (int oo = 0; oo < MIP; ++oo) a += wr[oo] * yt[(pp + 3) * 64 + oo];
        lt2[t] = a;
    }
    __syncthreads();
    // lwgt2: H side taps ky*7+3, W side taps 21+kx
    for (int idx = t; idx < 448; idx += 256) {
        int pp = idx / 28, m = idx - pp * 28;
        int g = m / 7, kk = m - g * 7;
        int wq = side ? (g * 49 + 21 + kk) : (g * 49 + kk * 7 + 3);
        float a = bb2[wq];
        const float* wr = ww2 + wq * 16;
        #pragma unroll
        for (int r = 0; r < 16; ++r) a += wr[r] * lt2[pp * 16 + r];
        lwgt2[idx] = a;
    }
    __syncthreads();
    // lz: involution over the half (zero outside [lo, lo+96))
    for (int idx = t; idx < 1024; idx += 256) {
        int pp = idx >> 6, ch = idx & 63;
        int g = ch >> 4;
        float a = 0.f;
        #pragma unroll
        for (int k = 0; k < KK; ++k) {
            int pos = p0 + pp + k - 3;
            float v = (pos >= lo && pos < lo + HW) ? yt[(pp + k) * 64 + ch] : 0.f;
            a += lwgt2[pp * 28 + g * 7 + k] * v;
        }
        lz[idx] = a;
    }
    __syncthreads();
    // final conv 64->256 + sigmoid; thread t = co, wf row L1-hot across 16 pp
    {
        int co = t;
        float accf[16];
        float bfv = bf[co];
        #pragma unroll
        for (int pp = 0; pp < 16; ++pp) accf[pp] = bfv;
        const float* wr = wf + co * MIP;
        for (int ch = 0; ch < MIP; ++ch) {
            float wv = wr[ch];
            #pragma unroll
            for (int pp = 0; pp < 16; ++pp)
                accf[pp] += wv * lz[pp * 64 + ch];
        }
        float* dst = side ? a_w : a_h;
        size_t basep = ((size_t)n * C_IN + co) * HW + (p0 - lo);
        #pragma unroll
        for (int pp = 0; pp < 16; ++pp)
            dst[basep + pp] = 1.f / (1.f + __expf(-accf[pp]));
    }
}

// ---------------------------------------------------------------------------
// Kernel C: out = x * a_w[j] * a_h[i], per-plane, float4, NT stores
// ---------------------------------------------------------------------------
__global__ void apply_kernel(const float* __restrict__ x,
                             const float* __restrict__ a_h, const float* __restrict__ a_w,
                             float* __restrict__ out) {
    int plane = blockIdx.x;   // n*256 + c
    const floatx4* xp = (const floatx4*)(x + (size_t)plane * (HW * HW));
    floatx4* op = (floatx4*)(out + (size_t)plane * (HW * HW));
    __shared__ float sah[HW];
    __shared__ float saw[HW];
    int t = threadIdx.x;
    if (t < HW) {
        sah[t] = a_h[(size_t)plane * HW + t];
        saw[t] = a_w[(size_t)plane * HW + t];
    }
    __syncthreads();
    #pragma unroll
    for (int k = 0; k < 9; ++k) {
        int idx = t + k * 256;          // float4 index, 2304 per plane
        floatx4 v = xp[idx];
        int row = idx / 24;
        int c4 = (idx - row * 24) * 4;
        float ah = sah[row];
        v.x *= ah * saw[c4 + 0];
        v.y *= ah * saw[c4 + 1];
        v.z *= ah * saw[c4 + 2];
        v.w *= ah * saw[c4 + 3];
        __builtin_nontemporal_store(v, &op[idx]);
    }
}

extern "C" void kernel_launch(void* const* d_in, const int* in_sizes, int n_in,
                              void* d_out, int out_size, void* d_ws, size_t ws_size,
                              hipStream_t stream) {
    const float* x      = (const float*)d_in[0];
    const float* w_c1   = (const float*)d_in[1];
    const float* b_c1   = (const float*)d_in[2];
    const float* i1_w1  = (const float*)d_in[3];
    const float* i1_b1  = (const float*)d_in[4];
    const float* i1_w2  = (const float*)d_in[5];
    const float* i1_b2  = (const float*)d_in[6];
    const float* bn_g   = (const float*)d_in[7];
    const float* bn_b   = (const float*)d_in[8];
    const float* bn_m   = (const float*)d_in[9];
    const float* bn_v   = (const float*)d_in[10];
    const float* ih_w1  = (const float*)d_in[11];
    const float* ih_b1  = (const float*)d_in[12];
    const float* ih_w2  = (const float*)d_in[13];
    const float* ih_b2  = (const float*)d_in[14];
    const float* w_h    = (const float*)d_in[15];
    const float* b_h    = (const float*)d_in[16];
    const float* iw_w1  = (const float*)d_in[17];
    const float* iw_b1  = (const float*)d_in[18];
    const float* iw_w2  = (const float*)d_in[19];
    const float* iw_b2  = (const float*)d_in[20];
    const float* w_w    = (const float*)d_in[21];
    const float* b_w    = (const float*)d_in[22];
    float* out = (float*)d_out;

    float* ws = (float*)d_ws;
    float* pooled = ws;                       // 786432
    float* a_h    = pooled + 786432;          // 393216
    float* a_w    = a_h + 393216;             // 393216

    pool_kernel<<<dim3(N_B * C_IN), dim3(256), 0, stream>>>(x, pooled);
    megamid_kernel<<<dim3(12, N_B), dim3(256), 0, stream>>>(
        pooled, w_c1, b_c1, i1_w1, i1_b1, i1_w2, i1_b2,
        bn_g, bn_b, bn_m, bn_v,
        ih_w1, ih_b1, ih_w2, ih_b2, w_h, b_h,
        iw_w1, iw_b1, iw_w2, iw_b2, w_w, b_w, a_h, a_w);
    apply_kernel<<<dim3(N_B * C_IN), dim3(256), 0, stream>>>(x, a_h, a_w, out);
}